// Round 1
// baseline (587.892 us; speedup 1.0000x reference)
//
#include <hip/hip_runtime.h>

#define B_ 4
#define N_ 1024
#define C_ 768
#define H_ 12
#define D_ 64

// ---------------- generic tiled fp32 GEMM: C = A[M,K] @ W[K,N] + bias ----------------
// 64x64 tile, BK=16, 256 threads, 4x4 per thread. M,N multiples of 64; K multiple of 16.
__global__ __launch_bounds__(256) void gemm_xw(const float* __restrict__ A,
                                               const float* __restrict__ W,
                                               const float* __restrict__ bias,
                                               float* __restrict__ Cmat,
                                               int M, int N, int K) {
    __shared__ float As[16][64];   // As[k][m]
    __shared__ float Bs[16][64];   // Bs[k][n]
    const int tid = threadIdx.x;
    const int tx = tid & 15, ty = tid >> 4;
    const int m0 = blockIdx.y * 64, n0 = blockIdx.x * 64;
    const int lr  = tid >> 2;          // 0..63 (tile row)
    const int lc4 = (tid & 3) * 4;     // 0,4,8,12 (k-col group)
    const int lkB = tid >> 4;          // 0..15
    const int lnB = (tid & 15) * 4;    // 0..60
    float acc[4][4] = {};
    for (int k0 = 0; k0 < K; k0 += 16) {
        float4 a = *(const float4*)&A[(size_t)(m0 + lr) * K + k0 + lc4];
        As[lc4 + 0][lr] = a.x; As[lc4 + 1][lr] = a.y;
        As[lc4 + 2][lr] = a.z; As[lc4 + 3][lr] = a.w;
        float4 b = *(const float4*)&W[(size_t)(k0 + lkB) * N + n0 + lnB];
        *(float4*)&Bs[lkB][lnB] = b;
        __syncthreads();
        #pragma unroll
        for (int kk = 0; kk < 16; ++kk) {
            float ra[4], rb[4];
            #pragma unroll
            for (int i = 0; i < 4; ++i) ra[i] = As[kk][ty * 4 + i];
            #pragma unroll
            for (int j = 0; j < 4; ++j) rb[j] = Bs[kk][tx * 4 + j];
            #pragma unroll
            for (int i = 0; i < 4; ++i)
                #pragma unroll
                for (int j = 0; j < 4; ++j)
                    acc[i][j] += ra[i] * rb[j];
        }
        __syncthreads();
    }
    float4 bv = *(const float4*)&bias[n0 + tx * 4];
    #pragma unroll
    for (int i = 0; i < 4; ++i) {
        float4 o = make_float4(acc[i][0] + bv.x, acc[i][1] + bv.y,
                               acc[i][2] + bv.z, acc[i][3] + bv.w);
        *(float4*)&Cmat[(size_t)(m0 + ty * 4 + i) * N + n0 + tx * 4] = o;
    }
}

// ---------------- batched QK^T: S[b,h,n,m] = 0.125 * sum_d Q[n,d]*K[m,d] ----------------
__global__ __launch_bounds__(256) void qk_kernel(const float* __restrict__ qkv,
                                                 float* __restrict__ attnP) {
    __shared__ float Qs[16][64];   // Qs[k][n]
    __shared__ float Ks[16][64];   // Ks[k][m]
    const int tid = threadIdx.x;
    const int tx = tid & 15, ty = tid >> 4;
    const int bh = blockIdx.z;
    const int b = bh / H_, h = bh % H_;
    const int n0 = blockIdx.y * 64, m0 = blockIdx.x * 64;
    const float* Qb = qkv + (size_t)b * N_ * (3 * C_) + h * D_;        // part 0
    const float* Kb = Qb + C_;                                          // part 1
    const int lr  = tid >> 2;
    const int lc4 = (tid & 3) * 4;
    float acc[4][4] = {};
    #pragma unroll
    for (int d0 = 0; d0 < D_; d0 += 16) {
        float4 q = *(const float4*)&Qb[(size_t)(n0 + lr) * (3 * C_) + d0 + lc4];
        Qs[lc4 + 0][lr] = q.x; Qs[lc4 + 1][lr] = q.y;
        Qs[lc4 + 2][lr] = q.z; Qs[lc4 + 3][lr] = q.w;
        float4 kk4 = *(const float4*)&Kb[(size_t)(m0 + lr) * (3 * C_) + d0 + lc4];
        Ks[lc4 + 0][lr] = kk4.x; Ks[lc4 + 1][lr] = kk4.y;
        Ks[lc4 + 2][lr] = kk4.z; Ks[lc4 + 3][lr] = kk4.w;
        __syncthreads();
        #pragma unroll
        for (int kk = 0; kk < 16; ++kk) {
            float ra[4], rb[4];
            #pragma unroll
            for (int i = 0; i < 4; ++i) ra[i] = Qs[kk][ty * 4 + i];
            #pragma unroll
            for (int j = 0; j < 4; ++j) rb[j] = Ks[kk][tx * 4 + j];
            #pragma unroll
            for (int i = 0; i < 4; ++i)
                #pragma unroll
                for (int j = 0; j < 4; ++j)
                    acc[i][j] += ra[i] * rb[j];
        }
        __syncthreads();
    }
    #pragma unroll
    for (int i = 0; i < 4; ++i) {
        float4 o = make_float4(acc[i][0] * 0.125f, acc[i][1] * 0.125f,
                               acc[i][2] * 0.125f, acc[i][3] * 0.125f);
        *(float4*)&attnP[((size_t)bh * N_ + n0 + ty * 4 + i) * N_ + m0 + tx * 4] = o;
    }
}

// ------- fused talking-heads: mix1 (W_l) -> softmax(m) -> mix2 (W_w), in place -------
// one block per (b,n) row; reads S[h][0..1023] for all 12 h, writes U[k][0..1023].
__global__ __launch_bounds__(256) void talking_softmax(float* __restrict__ attnP,
        const float* __restrict__ Wl, const float* __restrict__ bl,
        const float* __restrict__ Ww, const float* __restrict__ bw) {
    __shared__ float S[H_][N_];            // 48 KB
    __shared__ float Wl_s[H_ * H_], Ww_s[H_ * H_];
    __shared__ float bl_s[H_], bw_s[H_];
    __shared__ float redA[H_][4], redB[H_][4];
    const int tid = threadIdx.x;
    const int r = blockIdx.x;
    const int b = r >> 10, n = r & 1023;
    if (tid < H_ * H_) { Wl_s[tid] = Wl[tid]; Ww_s[tid] = Ww[tid]; }
    if (tid < H_)      { bl_s[tid] = bl[tid]; bw_s[tid] = bw[tid]; }
    const size_t rowbase = ((size_t)(b * H_) * N_ + n) * N_;   // plane stride N_*N_
    #pragma unroll
    for (int h = 0; h < H_; ++h)
        *(float4*)&S[h][tid * 4] =
            *(const float4*)&attnP[rowbase + (size_t)h * N_ * N_ + tid * 4];
    __syncthreads();

    // mix1: T[k][j] = b_l[k] + sum_h S[h][m] * W_l[h,k]
    float T[48];
    #pragma unroll
    for (int k = 0; k < H_; ++k) {
        float bk = bl_s[k];
        T[k*4+0] = bk; T[k*4+1] = bk; T[k*4+2] = bk; T[k*4+3] = bk;
    }
    #pragma unroll
    for (int h = 0; h < H_; ++h) {
        float4 sv = *(const float4*)&S[h][tid * 4];
        #pragma unroll
        for (int k = 0; k < H_; ++k) {
            float w = Wl_s[h * H_ + k];
            T[k*4+0] += sv.x * w; T[k*4+1] += sv.y * w;
            T[k*4+2] += sv.z * w; T[k*4+3] += sv.w * w;
        }
    }

    const int lane = tid & 63, wv = tid >> 6;
    // row max per k
    #pragma unroll
    for (int k = 0; k < H_; ++k) {
        float m = fmaxf(fmaxf(T[k*4+0], T[k*4+1]), fmaxf(T[k*4+2], T[k*4+3]));
        #pragma unroll
        for (int off = 32; off > 0; off >>= 1) m = fmaxf(m, __shfl_xor(m, off));
        if (lane == 0) redA[k][wv] = m;
    }
    __syncthreads();
    float pmax[12];
    #pragma unroll
    for (int k = 0; k < H_; ++k)
        pmax[k] = fmaxf(fmaxf(redA[k][0], redA[k][1]), fmaxf(redA[k][2], redA[k][3]));
    // exp + row sum
    #pragma unroll
    for (int k = 0; k < H_; ++k) {
        T[k*4+0] = __expf(T[k*4+0] - pmax[k]);
        T[k*4+1] = __expf(T[k*4+1] - pmax[k]);
        T[k*4+2] = __expf(T[k*4+2] - pmax[k]);
        T[k*4+3] = __expf(T[k*4+3] - pmax[k]);
        float s = (T[k*4+0] + T[k*4+1]) + (T[k*4+2] + T[k*4+3]);
        #pragma unroll
        for (int off = 32; off > 0; off >>= 1) s += __shfl_xor(s, off);
        if (lane == 0) redB[k][wv] = s;
    }
    __syncthreads();
    #pragma unroll
    for (int k = 0; k < H_; ++k) {
        float inv = 1.0f / ((redB[k][0] + redB[k][1]) + (redB[k][2] + redB[k][3]));
        T[k*4+0] *= inv; T[k*4+1] *= inv; T[k*4+2] *= inv; T[k*4+3] *= inv;
    }
    // mix2 + store: U[jj][m] = b_w[jj] + sum_k P[k][m] * W_w[k,jj]
    #pragma unroll
    for (int jj = 0; jj < H_; ++jj) {
        float u0 = bw_s[jj], u1 = u0, u2 = u0, u3 = u0;
        #pragma unroll
        for (int k = 0; k < H_; ++k) {
            float w = Ww_s[k * H_ + jj];
            u0 += T[k*4+0] * w; u1 += T[k*4+1] * w;
            u2 += T[k*4+2] * w; u3 += T[k*4+3] * w;
        }
        *(float4*)&attnP[rowbase + (size_t)jj * N_ * N_ + tid * 4] =
            make_float4(u0, u1, u2, u3);
    }
}

// ---------------- batched PV: outh[b,n,h*64+d] = sum_m U[b,h,n,m] * V[b,h,m,d] ----------------
__global__ __launch_bounds__(256) void pv_kernel(const float* __restrict__ attnP,
                                                 const float* __restrict__ qkv,
                                                 float* __restrict__ outh) {
    __shared__ float As[16][64];   // As[k][n]
    __shared__ float Vs[16][64];   // Vs[k][d]
    const int tid = threadIdx.x;
    const int tx = tid & 15, ty = tid >> 4;
    const int bh = blockIdx.y;
    const int b = bh / H_, h = bh % H_;
    const int n0 = blockIdx.x * 64;
    const float* Ab = attnP + (size_t)bh * N_ * N_;
    const float* Vb = qkv + (size_t)b * N_ * (3 * C_) + 2 * C_ + h * D_;
    const int lr  = tid >> 2;
    const int lc4 = (tid & 3) * 4;
    const int lkB = tid >> 4;
    const int lnB = (tid & 15) * 4;
    float acc[4][4] = {};
    for (int k0 = 0; k0 < N_; k0 += 16) {
        float4 a = *(const float4*)&Ab[(size_t)(n0 + lr) * N_ + k0 + lc4];
        As[lc4 + 0][lr] = a.x; As[lc4 + 1][lr] = a.y;
        As[lc4 + 2][lr] = a.z; As[lc4 + 3][lr] = a.w;
        float4 v = *(const float4*)&Vb[(size_t)(k0 + lkB) * (3 * C_) + lnB];
        *(float4*)&Vs[lkB][lnB] = v;
        __syncthreads();
        #pragma unroll
        for (int kk = 0; kk < 16; ++kk) {
            float ra[4], rb[4];
            #pragma unroll
            for (int i = 0; i < 4; ++i) ra[i] = As[kk][ty * 4 + i];
            #pragma unroll
            for (int j = 0; j < 4; ++j) rb[j] = Vs[kk][tx * 4 + j];
            #pragma unroll
            for (int i = 0; i < 4; ++i)
                #pragma unroll
                for (int j = 0; j < 4; ++j)
                    acc[i][j] += ra[i] * rb[j];
        }
        __syncthreads();
    }
    #pragma unroll
    for (int i = 0; i < 4; ++i) {
        *(float4*)&outh[((size_t)b * N_ + n0 + ty * 4 + i) * C_ + h * D_ + tx * 4] =
            make_float4(acc[i][0], acc[i][1], acc[i][2], acc[i][3]);
    }
}

extern "C" void kernel_launch(void* const* d_in, const int* in_sizes, int n_in,
                              void* d_out, int out_size, void* d_ws, size_t ws_size,
                              hipStream_t stream) {
    const float* x     = (const float*)d_in[0];
    const float* Wqkv  = (const float*)d_in[1];
    const float* bqkv  = (const float*)d_in[2];
    const float* Wl    = (const float*)d_in[3];
    const float* bl    = (const float*)d_in[4];
    const float* Ww    = (const float*)d_in[5];
    const float* bw    = (const float*)d_in[6];
    const float* Wproj = (const float*)d_in[7];
    const float* bproj = (const float*)d_in[8];

    float* out   = (float*)d_out;
    float* attnP = out + (size_t)B_ * N_ * C_;          // attn section of d_out (also QK^T scratch)
    float* qkvb  = (float*)d_ws;                         // [B*N, 3C] = 9,437,184 floats
    float* outh  = qkvb + (size_t)B_ * N_ * 3 * C_;      // [B*N, C]  = 3,145,728 floats

    // 1. qkv = x @ W_qkv + b_qkv
    gemm_xw<<<dim3((3 * C_) / 64, (B_ * N_) / 64), 256, 0, stream>>>(
        x, Wqkv, bqkv, qkvb, B_ * N_, 3 * C_, C_);
    // 2. logits = scale * Q K^T  (into the attn section of d_out, used as scratch)
    qk_kernel<<<dim3(N_ / 64, N_ / 64, B_ * H_), 256, 0, stream>>>(qkvb, attnP);
    // 3. in-place: mix(W_l) -> softmax -> mix(W_w)  => final attn output
    talking_softmax<<<B_ * N_, 256, 0, stream>>>(attnP, Wl, bl, Ww, bw);
    // 4. outh = attn @ V
    pv_kernel<<<dim3(N_ / 64, B_ * H_), 256, 0, stream>>>(attnP, qkvb, outh);
    // 5. out = outh @ W_proj + b_proj
    gemm_xw<<<dim3(C_ / 64, (B_ * N_) / 64), 256, 0, stream>>>(
        outh, Wproj, bproj, out, B_ * N_, C_, C_);
}

// Round 2
// 259.577 us; speedup vs baseline: 2.2648x; 2.2648x over previous
//
#include <hip/hip_runtime.h>
#include <stdint.h>

#define B_ 4
#define N_ 1024
#define C_ 768
#define H_ 12
#define D_ 64
#define MT 4096   // B_*N_ tokens

typedef short bf16x8 __attribute__((ext_vector_type(8)));
typedef float f32x4  __attribute__((ext_vector_type(4)));
typedef unsigned short u16;

__device__ __forceinline__ u16 f2bf(float f) {
  union { float f; uint32_t u; } v; v.f = f;
  uint32_t u = v.u + 0x7FFFu + ((v.u >> 16) & 1u);   // RNE
  return (u16)(u >> 16);
}
__device__ __forceinline__ float bf2f(u16 h) {
  union { uint32_t u; float f; } v; v.u = ((uint32_t)h) << 16;
  return v.f;
}

__device__ __forceinline__ void gload16(const void* g, void* l) {
  __builtin_amdgcn_global_load_lds(
      (const __attribute__((address_space(1))) void*)g,
      (__attribute__((address_space(3))) void*)l, 16, 0, 0);
}

// stage ROWS x 64 bf16 tile (row-major, row stride ld elems) into LDS via global_load_lds.
// one instr = 1KB = 8 rows x 128B. LDS dest is wave-uniform; HW adds lane*16B.
template<int ROWS, int NW>
__device__ __forceinline__ void stage_bt(const u16* g, int ld, u16 (*lds)[64]) {
  const int lane = threadIdx.x & 63, wv = threadIdx.x >> 6;
  const int r8 = lane >> 3;          // 0..7 row within 8-row chunk
  const int c8 = (lane & 7) * 8;     // 0..56 elem offset (16B per lane)
  for (int i = wv; i < ROWS / 8; i += NW)
    gload16(g + (size_t)(i * 8 + r8) * ld + c8, &lds[i * 8][0]);
}

// one K=64 MFMA step: each wave computes a 64x64 sub-tile (4x4 frags of 16x16x32, 2 k-steps).
// A-frag: lane l holds A[l&15][8*(l>>4)+j]; B-frag (from B^T rows) symmetric.
// C/D: lane l reg r = D[(l>>4)*4 + r][l&15]   (guide-verified layout)
template<int WM, int WN>
__device__ __forceinline__ void mma_step(const u16 (*As)[64], const u16 (*Bs)[64],
                                         f32x4 acc[4][4]) {
  const int lane = threadIdx.x & 63, wv = threadIdx.x >> 6;
  const int wr = wv / WN, wc = wv % WN;
  const int g4 = lane >> 4, r16 = lane & 15;
  #pragma unroll
  for (int ks = 0; ks < 2; ++ks) {
    bf16x8 a[4], b[4];
    #pragma unroll
    for (int mi = 0; mi < 4; ++mi)
      a[mi] = *(const bf16x8*)&As[wr * 64 + mi * 16 + r16][ks * 32 + g4 * 8];
    #pragma unroll
    for (int ni = 0; ni < 4; ++ni)
      b[ni] = *(const bf16x8*)&Bs[wc * 64 + ni * 16 + r16][ks * 32 + g4 * 8];
    #pragma unroll
    for (int mi = 0; mi < 4; ++mi)
      #pragma unroll
      for (int ni = 0; ni < 4; ++ni)
        acc[mi][ni] = __builtin_amdgcn_mfma_f32_16x16x32_bf16(a[mi], b[ni], acc[mi][ni], 0, 0, 0);
  }
}

// ---------------- prep: fp32 -> bf16 convert / transpose ----------------
__global__ __launch_bounds__(256) void cvt_bf16(const float* __restrict__ in,
                                                u16* __restrict__ out, int n4) {
  int i = blockIdx.x * 256 + threadIdx.x;
  if (i < n4) {
    float4 v = *(const float4*)&in[(size_t)i * 4];
    ushort4 o = make_ushort4(f2bf(v.x), f2bf(v.y), f2bf(v.z), f2bf(v.w));
    *(ushort4*)&out[(size_t)i * 4] = o;
  }
}

// out[Cc][R] = in[R][Cc]^T, bf16-converted. block (32,8), grid (Cc/32, R/32).
__global__ __launch_bounds__(256) void transpose_bf16(const float* __restrict__ in,
                                                      u16* __restrict__ out, int R, int Cc) {
  __shared__ float tile[32][33];
  const int bx = blockIdx.x * 32, by = blockIdx.y * 32;
  const int tx = threadIdx.x, ty = threadIdx.y;
  #pragma unroll
  for (int i = 0; i < 32; i += 8)
    tile[ty + i][tx] = in[(size_t)(by + ty + i) * Cc + bx + tx];
  __syncthreads();
  #pragma unroll
  for (int i = 0; i < 32; i += 8)
    out[(size_t)(bx + ty + i) * R + by + tx] = f2bf(tile[tx][ty + i]);
}

// ---------------- qkv GEMM: [4096,768] x [768,2304] + bias ----------------
// writes Qb (bf16, *0.125), Kb (bf16), Vt (bf16 transposed [b,h,d,n])
__global__ __launch_bounds__(256) void qkv_gemm(const u16* __restrict__ xbf,
    const u16* __restrict__ Wt, const float* __restrict__ bias,
    u16* __restrict__ Qb, u16* __restrict__ Kb, u16* __restrict__ Vt) {
  __shared__ u16 As[128][64], Bs[128][64];
  f32x4 acc[4][4] = {};
  const int row0 = blockIdx.y * 128, col0 = blockIdx.x * 128;
  const u16* Ab = xbf + (size_t)row0 * C_;
  const u16* Bb = Wt + (size_t)col0 * C_;
  for (int k0 = 0; k0 < C_; k0 += 64) {
    stage_bt<128, 4>(Ab + k0, C_, As);
    stage_bt<128, 4>(Bb + k0, C_, Bs);
    __syncthreads();
    mma_step<2, 2>(As, Bs, acc);
    __syncthreads();
  }
  const int lane = threadIdx.x & 63, wv = threadIdx.x >> 6;
  const int wr = wv >> 1, wc = wv & 1;
  const int part = col0 / C_;    // block fully inside one of q/k/v (768 % 128 == 0)
  #pragma unroll
  for (int mi = 0; mi < 4; ++mi)
  #pragma unroll
  for (int ni = 0; ni < 4; ++ni) {
    const int c = col0 + wc * 64 + ni * 16 + (lane & 15);
    const int rb = row0 + wr * 64 + mi * 16 + (lane >> 4) * 4;
    const float bv = bias[c];
    #pragma unroll
    for (int rr = 0; rr < 4; ++rr) {
      const int row = rb + rr;
      const float v = acc[mi][ni][rr] + bv;
      if (part == 0) {
        Qb[(size_t)row * C_ + c] = f2bf(v * 0.125f);
      } else if (part == 1) {
        Kb[(size_t)row * C_ + (c - C_)] = f2bf(v);
      } else {
        const int cc = c - 2 * C_;   // h*64 + d
        Vt[(((size_t)(row >> 10) * H_ + (cc >> 6)) * D_ + (cc & 63)) * N_ + (row & 1023)] = f2bf(v);
      }
    }
  }
}

// ---------------- QK^T (batched over b,h): logits fp32 into d_out attn region ----------------
__global__ __launch_bounds__(256) void qk_gemm(const u16* __restrict__ Qb,
    const u16* __restrict__ Kb, float* __restrict__ Sf) {
  __shared__ u16 As[128][64], Bs[128][64];
  f32x4 acc[4][4] = {};
  const int z = blockIdx.z, b = z / H_, h = z % H_;
  const int row0 = blockIdx.y * 128, col0 = blockIdx.x * 128;
  const u16* Ab = Qb + (size_t)(b * N_ + row0) * C_ + h * D_;
  const u16* Bb = Kb + (size_t)(b * N_ + col0) * C_ + h * D_;
  stage_bt<128, 4>(Ab, C_, As);
  stage_bt<128, 4>(Bb, C_, Bs);
  __syncthreads();
  mma_step<2, 2>(As, Bs, acc);
  float* Sp = Sf + (size_t)z * N_ * N_;
  const int lane = threadIdx.x & 63, wv = threadIdx.x >> 6;
  const int wr = wv >> 1, wc = wv & 1;
  #pragma unroll
  for (int mi = 0; mi < 4; ++mi)
  #pragma unroll
  for (int ni = 0; ni < 4; ++ni) {
    const int c = col0 + wc * 64 + ni * 16 + (lane & 15);
    const int rb = row0 + wr * 64 + mi * 16 + (lane >> 4) * 4;
    #pragma unroll
    for (int rr = 0; rr < 4; ++rr)
      Sp[(size_t)(rb + rr) * N_ + c] = acc[mi][ni][rr];
  }
}

// ------- fused talking-heads: mix1 -> softmax -> mix2, fp32 in place (round-1 proven) -------
__global__ __launch_bounds__(256) void talking_softmax(float* __restrict__ attnP,
        const float* __restrict__ Wl, const float* __restrict__ bl,
        const float* __restrict__ Ww, const float* __restrict__ bw) {
    __shared__ float S[H_][N_];            // 48 KB
    __shared__ float Wl_s[H_ * H_], Ww_s[H_ * H_];
    __shared__ float bl_s[H_], bw_s[H_];
    __shared__ float redA[H_][4], redB[H_][4];
    const int tid = threadIdx.x;
    const int r = blockIdx.x;
    const int b = r >> 10, n = r & 1023;
    if (tid < H_ * H_) { Wl_s[tid] = Wl[tid]; Ww_s[tid] = Ww[tid]; }
    if (tid < H_)      { bl_s[tid] = bl[tid]; bw_s[tid] = bw[tid]; }
    const size_t rowbase = ((size_t)(b * H_) * N_ + n) * N_;
    #pragma unroll
    for (int h = 0; h < H_; ++h)
        *(float4*)&S[h][tid * 4] =
            *(const float4*)&attnP[rowbase + (size_t)h * N_ * N_ + tid * 4];
    __syncthreads();

    float T[48];
    #pragma unroll
    for (int k = 0; k < H_; ++k) {
        float bk = bl_s[k];
        T[k*4+0] = bk; T[k*4+1] = bk; T[k*4+2] = bk; T[k*4+3] = bk;
    }
    #pragma unroll
    for (int h = 0; h < H_; ++h) {
        float4 sv = *(const float4*)&S[h][tid * 4];
        #pragma unroll
        for (int k = 0; k < H_; ++k) {
            float w = Wl_s[h * H_ + k];
            T[k*4+0] += sv.x * w; T[k*4+1] += sv.y * w;
            T[k*4+2] += sv.z * w; T[k*4+3] += sv.w * w;
        }
    }

    const int lane = tid & 63, wv = tid >> 6;
    #pragma unroll
    for (int k = 0; k < H_; ++k) {
        float m = fmaxf(fmaxf(T[k*4+0], T[k*4+1]), fmaxf(T[k*4+2], T[k*4+3]));
        #pragma unroll
        for (int off = 32; off > 0; off >>= 1) m = fmaxf(m, __shfl_xor(m, off));
        if (lane == 0) redA[k][wv] = m;
    }
    __syncthreads();
    float pmax[12];
    #pragma unroll
    for (int k = 0; k < H_; ++k)
        pmax[k] = fmaxf(fmaxf(redA[k][0], redA[k][1]), fmaxf(redA[k][2], redA[k][3]));
    #pragma unroll
    for (int k = 0; k < H_; ++k) {
        T[k*4+0] = __expf(T[k*4+0] - pmax[k]);
        T[k*4+1] = __expf(T[k*4+1] - pmax[k]);
        T[k*4+2] = __expf(T[k*4+2] - pmax[k]);
        T[k*4+3] = __expf(T[k*4+3] - pmax[k]);
        float s = (T[k*4+0] + T[k*4+1]) + (T[k*4+2] + T[k*4+3]);
        #pragma unroll
        for (int off = 32; off > 0; off >>= 1) s += __shfl_xor(s, off);
        if (lane == 0) redB[k][wv] = s;
    }
    __syncthreads();
    #pragma unroll
    for (int k = 0; k < H_; ++k) {
        float inv = 1.0f / ((redB[k][0] + redB[k][1]) + (redB[k][2] + redB[k][3]));
        T[k*4+0] *= inv; T[k*4+1] *= inv; T[k*4+2] *= inv; T[k*4+3] *= inv;
    }
    #pragma unroll
    for (int jj = 0; jj < H_; ++jj) {
        float u0 = bw_s[jj], u1 = u0, u2 = u0, u3 = u0;
        #pragma unroll
        for (int k = 0; k < H_; ++k) {
            float w = Ww_s[k * H_ + jj];
            u0 += T[k*4+0] * w; u1 += T[k*4+1] * w;
            u2 += T[k*4+2] * w; u3 += T[k*4+3] * w;
        }
        *(float4*)&attnP[rowbase + (size_t)jj * N_ * N_ + tid * 4] =
            make_float4(u0, u1, u2, u3);
    }
}

// ---------------- PV (batched): A = fp32 attn (converted on the fly), B = Vt bf16 ----------------
__global__ __launch_bounds__(128) void pv_gemm(const float* __restrict__ Pf,
    const u16* __restrict__ Vt, u16* __restrict__ Oh) {
  __shared__ u16 As[128][64], Bs[64][64];
  f32x4 acc[4][4] = {};
  const int z = blockIdx.y, b = z / H_, h = z % H_;
  const int row0 = blockIdx.x * 128;
  const float* Ap = Pf + (size_t)z * N_ * N_ + (size_t)row0 * N_;
  const u16* Bb = Vt + (size_t)z * D_ * N_;
  const int tid = threadIdx.x;
  for (int k0 = 0; k0 < N_; k0 += 64) {
    #pragma unroll
    for (int i = 0; i < 16; ++i) {     // 128 rows x 64 cols, 128 threads: 8 rows/pass
      const int row = i * 8 + (tid >> 4);
      const int c4 = (tid & 15) * 4;
      float4 v = *(const float4*)&Ap[(size_t)row * N_ + k0 + c4];
      *(ushort4*)&As[row][c4] = make_ushort4(f2bf(v.x), f2bf(v.y), f2bf(v.z), f2bf(v.w));
    }
    stage_bt<64, 2>(Bb + k0, N_, Bs);
    __syncthreads();
    mma_step<2, 1>(As, Bs, acc);
    __syncthreads();
  }
  const int lane = tid & 63, wv = tid >> 6;   // wr = wv, wc = 0
  #pragma unroll
  for (int mi = 0; mi < 4; ++mi)
  #pragma unroll
  for (int ni = 0; ni < 4; ++ni) {
    const int c = ni * 16 + (lane & 15);      // d in [0,64)
    const int rb = row0 + wv * 64 + mi * 16 + (lane >> 4) * 4;
    #pragma unroll
    for (int rr = 0; rr < 4; ++rr)
      Oh[(size_t)(b * N_ + rb + rr) * C_ + h * D_ + c] = f2bf(acc[mi][ni][rr]);
  }
}

// ---------------- proj GEMM: [4096,768] x [768,768] + bias -> fp32 out ----------------
__global__ __launch_bounds__(128) void proj_gemm(const u16* __restrict__ Oh,
    const u16* __restrict__ Wt, const float* __restrict__ bias, float* __restrict__ out) {
  __shared__ u16 As[64][64], Bs[128][64];
  f32x4 acc[4][4] = {};
  const int row0 = blockIdx.y * 64, col0 = blockIdx.x * 128;
  const u16* Ab = Oh + (size_t)row0 * C_;
  const u16* Bb = Wt + (size_t)col0 * C_;
  for (int k0 = 0; k0 < C_; k0 += 64) {
    stage_bt<64, 2>(Ab + k0, C_, As);
    stage_bt<128, 2>(Bb + k0, C_, Bs);
    __syncthreads();
    mma_step<1, 2>(As, Bs, acc);
    __syncthreads();
  }
  const int lane = threadIdx.x & 63, wv = threadIdx.x >> 6;
  const int wc = wv & 1;   // wr = 0
  #pragma unroll
  for (int mi = 0; mi < 4; ++mi)
  #pragma unroll
  for (int ni = 0; ni < 4; ++ni) {
    const int c = col0 + wc * 64 + ni * 16 + (lane & 15);
    const int rb = row0 + mi * 16 + (lane >> 4) * 4;
    const float bv = bias[c];
    #pragma unroll
    for (int rr = 0; rr < 4; ++rr)
      out[(size_t)(rb + rr) * C_ + c] = acc[mi][ni][rr] + bv;
  }
}

extern "C" void kernel_launch(void* const* d_in, const int* in_sizes, int n_in,
                              void* d_out, int out_size, void* d_ws, size_t ws_size,
                              hipStream_t stream) {
  const float* x     = (const float*)d_in[0];
  const float* Wqkv  = (const float*)d_in[1];
  const float* bqkv  = (const float*)d_in[2];
  const float* Wl    = (const float*)d_in[3];
  const float* bl    = (const float*)d_in[4];
  const float* Ww    = (const float*)d_in[5];
  const float* bw    = (const float*)d_in[6];
  const float* Wproj = (const float*)d_in[7];
  const float* bproj = (const float*)d_in[8];

  float* out   = (float*)d_out;
  float* attnP = out + (size_t)MT * C_;            // logits scratch == final attn output

  u16* xbf = (u16*)d_ws;                           // [4096][768]
  u16* Wqt = xbf + (size_t)MT * C_;                // [2304][768] = W_qkv^T
  u16* Wpt = Wqt + (size_t)3 * C_ * C_;            // [768][768]  = W_proj^T
  u16* Qb  = Wpt + (size_t)C_ * C_;                // [4096][768] (scaled)
  u16* Kb  = Qb + (size_t)MT * C_;                 // [4096][768]
  u16* Vtb = Kb + (size_t)MT * C_;                 // [b][h][d][n]
  u16* Oh  = Vtb + (size_t)MT * C_;                // [4096][768]
  // total ws use: ~36.2 MB

  cvt_bf16<<<(MT * C_ / 4 + 255) / 256, 256, 0, stream>>>(x, xbf, MT * C_ / 4);
  transpose_bf16<<<dim3(3 * C_ / 32, C_ / 32), dim3(32, 8), 0, stream>>>(Wqkv, Wqt, C_, 3 * C_);
  transpose_bf16<<<dim3(C_ / 32, C_ / 32), dim3(32, 8), 0, stream>>>(Wproj, Wpt, C_, C_);

  qkv_gemm<<<dim3(3 * C_ / 128, MT / 128), 256, 0, stream>>>(xbf, Wqt, bqkv, Qb, Kb, Vtb);
  qk_gemm<<<dim3(N_ / 128, N_ / 128, B_ * H_), 256, 0, stream>>>(Qb, Kb, attnP);
  talking_softmax<<<MT, 256, 0, stream>>>(attnP, Wl, bl, Ww, bw);
  pv_gemm<<<dim3(N_ / 128, B_ * H_), 128, 0, stream>>>(attnP, Vtb, Oh);
  proj_gemm<<<dim3(C_ / 128, MT / 64), 128, 0, stream>>>(Oh, Wpt, bproj, out);
}